// Round 1
// 461.575 us; speedup vs baseline: 1.0429x; 1.0429x over previous
//
#include <hip/hip_runtime.h>

// CompressionLayer: B=256, H=W=512, 16x16 chunks -> N=1024, KIN=256, KOUT=64.
// Per chunk n: Y[b,o] = relu( sum_k X[b,n,k]*W[n,o,k] + bias[n,o] ), scatter to
// out[b, (ci*8+oh)*256 + cj*8+ow], o = oh*8+ow, n = ci*32+cj.
// dtypes: x/Wk/bk/out all fp32 in memory; harness threshold is bf16-tolerant,
// so internal compute uses bf16 MFMA (fp32 accumulate).
//
// Memory-bound: 256+64+64 MiB ~= 384 MiB -> ~61 us floor @ 6.3 TB/s.
// R1 diagnosis: latency-bound (28% HBM, VGPR=64 -> only ~6 loads in flight/wave).
// Fix: hoist ALL 16 x-loads per batch-tile into registers (16 dwordx4 in
// flight/wave), and swap MFMA operands so D is [o][batch] -> float4 stores.

typedef __bf16 bf16x8 __attribute__((ext_vector_type(8)));  // MFMA A/B operand (4 VGPRs)
typedef float  f32x4  __attribute__((ext_vector_type(4)));  // MFMA C/D

constexpr int LDW = 264;  // Ws row stride in bf16 elems; 528 B row, 16B-aligned, breaks pow2 banks

union bfpack {                      // explicit bit-level bridge fp32->bf16 vec
  unsigned short s[8];
  bf16x8 v;
};

__device__ __forceinline__ unsigned short f2bf(float f) {
  union { float f; unsigned u; } v; v.f = f;
  unsigned r = v.u + 0x7fffu + ((v.u >> 16) & 1u);   // RNE (inputs finite)
  return (unsigned short)(r >> 16);
}

__global__ __launch_bounds__(256, 4) void comp_kernel(
    const float* __restrict__ x, const float* __restrict__ Wk,
    const float* __restrict__ bk, float* __restrict__ out) {
  __shared__ unsigned short Ws[64 * LDW];   // W[n] bf16, [o][k] row-major padded
  __shared__ float bs[64];

  const int bid = blockIdx.x;
  // XCD swizzle: round-robin dispatch (bid%8 -> XCD). n = xcd*128 + g, so
  // consecutive g on one XCD => consecutive cj => shared x/out cache lines
  // stay within one XCD's L2.
  const int n  = ((bid & 7) << 7) | (bid >> 3);
  const int ci = n >> 5, cj = n & 31;
  const int t = threadIdx.x;
  const int wave = t >> 6, lane = t & 63;
  const int m15 = lane & 15, quad = lane >> 4;

  // ---- stage Wk[n] (64x256 fp32 = 64 KB) -> bf16 LDS; 32 B/lane/iter coalesced ----
  const float4* wsrc = (const float4*)(Wk + (size_t)n * (64 * 256));
  #pragma unroll
  for (int it = 0; it < 8; ++it) {
    int i2 = it * 512 + t * 2;          // float4 granule pair, [0,4096)
    float4 g0 = wsrc[i2];
    float4 g1 = wsrc[i2 + 1];
    int o = i2 >> 6, pos = (i2 & 63) * 4;
    bfpack p;
    p.s[0] = f2bf(g0.x); p.s[1] = f2bf(g0.y); p.s[2] = f2bf(g0.z); p.s[3] = f2bf(g0.w);
    p.s[4] = f2bf(g1.x); p.s[5] = f2bf(g1.y); p.s[6] = f2bf(g1.z); p.s[7] = f2bf(g1.w);
    *(bf16x8*)&Ws[o * LDW + pos] = p.v;  // 16 B LDS store
  }
  if (t < 64) bs[t] = bk[n * 64 + t];
  __syncthreads();   // the ONLY barrier

  // A-fragment base: k = ks*32 + quad*8 + j  =>  kh = 2*ks + (quad>>1), kw = (quad&1)*8
  const float* xb = x + (size_t)(ci * 16) * 512 + cj * 16
                      + (quad >> 1) * 512 + (quad & 1) * 8;

  for (int bp = 0; bp < 4; ++bp) {
    const int btile = bp * 64 + wave * 16;            // this wave's 16 batches
    const float* xp = xb + (size_t)(btile + m15) * (512 * 512);

    // ---- MLP: issue ALL 16 dwordx4 x-loads for this tile before any compute.
    // Static indices -> pure registers (64 VGPRs of data). sched_barrier keeps
    // the scheduler from sinking loads into the compute; progressive vmcnt
    // waits still overlap conversion of early ks with in-flight later loads.
    float4 v0[8], v1[8];
    #pragma unroll
    for (int ks = 0; ks < 8; ++ks) {
      v0[ks] = *(const float4*)(xp + ks * 1024);
      v1[ks] = *(const float4*)(xp + ks * 1024 + 4);
    }
    __builtin_amdgcn_sched_barrier(0);

    f32x4 acc[4] = {{0,0,0,0},{0,0,0,0},{0,0,0,0},{0,0,0,0}};

    #pragma unroll
    for (int ks = 0; ks < 8; ++ks) {
      bfpack a;
      a.s[0] = f2bf(v0[ks].x); a.s[1] = f2bf(v0[ks].y);
      a.s[2] = f2bf(v0[ks].z); a.s[3] = f2bf(v0[ks].w);
      a.s[4] = f2bf(v1[ks].x); a.s[5] = f2bf(v1[ks].y);
      a.s[6] = f2bf(v1[ks].z); a.s[7] = f2bf(v1[ks].w);

      const int ka = ks * 32 + quad * 8;
      bf16x8 bb[4];
      #pragma unroll
      for (int nt = 0; nt < 4; ++nt)     // W-operand: lane o-index = m15 -> o = nt*16+m15
        bb[nt] = *(const bf16x8*)&Ws[(nt * 16 + m15) * LDW + ka];
      // Swapped operands: A=W (rows=o), B=x (cols=batch) -> D[o][batch].
      // (A and B lane layouts are identical for 16x16x32, so swap is free.)
      #pragma unroll
      for (int nt = 0; nt < 4; ++nt)
        acc[nt] = __builtin_amdgcn_mfma_f32_16x16x32_bf16(bb[nt], a.v, acc[nt], 0, 0, 0);
    }

    // ---- epilogue: D row(o) = nt*16 + quad*4 + r, col(batch) = m15.
    // Each lane holds 4 consecutive o within one oh-row -> one float4 store
    // per nt (4 stores/lane/tile instead of 16 scalar stores).
    float* op = out + (size_t)(btile + m15) * 65536
                    + (size_t)(ci * 8) * 256 + cj * 8;
    #pragma unroll
    for (int nt = 0; nt < 4; ++nt) {
      const int o0 = nt * 16 + quad * 4;               // o0..o0+3, same oh row
      float4 b4 = *(const float4*)&bs[o0];             // LDS broadcast read
      float4 res;
      res.x = fmaxf(acc[nt][0] + b4.x, 0.f);
      res.y = fmaxf(acc[nt][1] + b4.y, 0.f);
      res.z = fmaxf(acc[nt][2] + b4.z, 0.f);
      res.w = fmaxf(acc[nt][3] + b4.w, 0.f);
      *(float4*)&op[(o0 >> 3) * 256 + (o0 & 7)] = res; // 16 B store, 16B-aligned
    }
  }
}

extern "C" void kernel_launch(void* const* d_in, const int* in_sizes, int n_in,
                              void* d_out, int out_size, void* d_ws, size_t ws_size,
                              hipStream_t stream) {
  const float* x  = (const float*)d_in[0];
  const float* Wk = (const float*)d_in[1];
  const float* bk = (const float*)d_in[2];
  float* out = (float*)d_out;
  comp_kernel<<<dim3(1024), dim3(256), 0, stream>>>(x, Wk, bk, out);
}

// Round 2
// 443.239 us; speedup vs baseline: 1.0860x; 1.0414x over previous
//
#include <hip/hip_runtime.h>

// CompressionLayer: B=256, H=W=512, 16x16 chunks -> N=1024, KIN=256, KOUT=64.
// Per chunk n: Y[b,o] = relu( sum_k X[b,n,k]*W[n,o,k] + bias[n,o] ), scatter to
// out[b, (ci*8+oh)*256 + cj*8+ow], o = oh*8+ow, n = ci*32+cj.
//
// R2 diagnosis: latency-bound; register-resident MLP capped (~4 KB/CU in
// flight, need ~12+). Fix: x staged via global_load_lds DMA into wave-private
// double-buffered LDS (zero main-loop barriers), 2-deep pipeline, counted
// vmcnt (never drained mid-loop). In-flight bytes now live in the DMA queue,
// not VGPRs. Source-side XOR swizzle (linear LDS dest) kills bank conflicts
// on the ds_read_b128 side.

typedef __bf16 bf16x8 __attribute__((ext_vector_type(8)));  // MFMA A/B operand
typedef float  f32x4  __attribute__((ext_vector_type(4)));  // MFMA C/D

constexpr int LDW = 264;  // Ws row stride (bf16): 528 B, 16B-aligned, rotates banks by 4/row

union bfpack { unsigned short s[8]; bf16x8 v; };

__device__ __forceinline__ unsigned short f2bf(float f) {
  union { float f; unsigned u; } v; v.f = f;
  unsigned r = v.u + 0x7fffu + ((v.u >> 16) & 1u);   // RNE (inputs finite)
  return (unsigned short)(r >> 16);
}

typedef __attribute__((address_space(1))) const void GV;
typedef __attribute__((address_space(3))) void LV;

__global__ __launch_bounds__(256, 2) void comp_kernel(
    const float* __restrict__ x, const float* __restrict__ Wk,
    const float* __restrict__ bk, float* __restrict__ out) {
  __shared__ unsigned short Ws[64 * LDW];            // 33792 B
  __shared__ float bs[64];                           //   256 B
  __shared__ __align__(16) float Xs[4][2][1024];     // 32768 B: per-wave dbuf, 4KB stages
  // total 66816 B -> 2 blocks/CU

  const int bid = blockIdx.x;
  // XCD swizzle: consecutive g on one XCD => consecutive cj => shared x/out
  // cache lines stay within one XCD's L2.
  const int n  = ((bid & 7) << 7) | (bid >> 3);
  const int ci = n >> 5, cj = n & 31;
  const int t = threadIdx.x;
  const int wave = t >> 6, lane = t & 63;
  const int m15 = lane & 15, quad = lane >> 4;

  const char* xbase = (const char*)x + (size_t)ci * 32768 + (size_t)cj * 64;
  const int b_hi = lane >> 4;          // batch sub-index within a 4-batch DMA slab
  const int rr = (lane & 15) * 16;     // byte pos within a 256B k-row

  // Issue one 4KB x-stage s: batches bp*64+wave*16+[0,16), k-local [q*64,q*64+64).
  // LDS dest is linear (lane*16); source address carries the XOR swizzle
  // (k-granule ^ (batch&7)<<4) so reads can be bank-conflict-free.
  auto stage_issue = [&](int s) {
    const int bp = s >> 2, q = s & 3;
    const int btile = bp * 64 + wave * 16;
    float* dst = &Xs[wave][s & 1][0];
    #pragma unroll
    for (int i = 0; i < 4; ++i) {
      const int b_it = i * 4 + b_hi;                 // batch within tile, 0..15
      const int ro = rr ^ ((b_it & 7) << 4);         // swizzled k-byte offset, 16B-granular
      const char* src = xbase + (size_t)(btile + b_it) * 1048576
                      + (size_t)((q * 4 + (ro >> 6)) * 2048 + (ro & 63));
      __builtin_amdgcn_global_load_lds((GV*)src, (LV*)(dst + i * 256), 16, 0, 0);
    }
  };

  // ---- prime the DMA pipeline (stages 0,1) before Ws staging; the barrier's
  // vmcnt(0) drain then guarantees both Ws and the first two x-stages landed.
  stage_issue(0);
  stage_issue(1);

  // ---- stage Wk[n] (64x256 fp32 = 64 KB) -> bf16 LDS ----
  const float4* wsrc = (const float4*)(Wk + (size_t)n * (64 * 256));
  #pragma unroll
  for (int it = 0; it < 8; ++it) {
    int i2 = it * 512 + t * 2;
    float4 g0 = wsrc[i2];
    float4 g1 = wsrc[i2 + 1];
    int o = i2 >> 6, pos = (i2 & 63) * 4;
    bfpack p;
    p.s[0] = f2bf(g0.x); p.s[1] = f2bf(g0.y); p.s[2] = f2bf(g0.z); p.s[3] = f2bf(g0.w);
    p.s[4] = f2bf(g1.x); p.s[5] = f2bf(g1.y); p.s[6] = f2bf(g1.z); p.s[7] = f2bf(g1.w);
    *(bf16x8*)&Ws[o * LDW + pos] = p.v;
  }
  if (t < 64) bs[t] = bk[n * 64 + t];
  __syncthreads();   // the ONLY barrier

  #pragma unroll
  for (int bp = 0; bp < 4; ++bp) {
    const int btile = bp * 64 + wave * 16;
    f32x4 acc[4] = {{0,0,0,0},{0,0,0,0},{0,0,0,0},{0,0,0,0}};

    #pragma unroll
    for (int q = 0; q < 4; ++q) {
      const int s = bp * 4 + q;
      // Counted waits, never vmcnt(0) mid-loop. FIFO tail at this point:
      //   q>=2 (or bp==0): [stage s+1] -> 4
      //   q<2  of bp>=1:   [stage s+1][4 epilogue stores][stage s+2-ish] -> 8
      //   s==15: nothing may remain.
      if (s == 15)              asm volatile("s_waitcnt vmcnt(0)" ::: "memory");
      else if (s >= 4 && q < 2) asm volatile("s_waitcnt vmcnt(8)" ::: "memory");
      else                      asm volatile("s_waitcnt vmcnt(4)" ::: "memory");
      __builtin_amdgcn_sched_barrier(0);

      const char* Xb = (const char*)&Xs[wave][s & 1][0];
      const int sw = (m15 & 7) << 4;
      #pragma unroll
      for (int ksl = 0; ksl < 2; ++ksl) {
        const int c = ksl * 128 + quad * 32;         // k bytes [c, c+32) of row m15
        float4 v0 = *(const float4*)(Xb + m15 * 256 + ((c)      ^ sw));
        float4 v1 = *(const float4*)(Xb + m15 * 256 + ((c + 16) ^ sw));
        bfpack a;
        a.s[0] = f2bf(v0.x); a.s[1] = f2bf(v0.y); a.s[2] = f2bf(v0.z); a.s[3] = f2bf(v0.w);
        a.s[4] = f2bf(v1.x); a.s[5] = f2bf(v1.y); a.s[6] = f2bf(v1.z); a.s[7] = f2bf(v1.w);

        const int ka = (q * 2 + ksl) * 32 + quad * 8;
        bf16x8 bb[4];
        #pragma unroll
        for (int nt = 0; nt < 4; ++nt)
          bb[nt] = *(const bf16x8*)&Ws[(nt * 16 + m15) * LDW + ka];
        // Swapped operands: A=W (rows=o), B=x (cols=batch) -> D[o][batch].
        #pragma unroll
        for (int nt = 0; nt < 4; ++nt)
          acc[nt] = __builtin_amdgcn_mfma_f32_16x16x32_bf16(bb[nt], a.v, acc[nt], 0, 0, 0);
      }

      if (s + 2 < 16) {
        // Pin FIFO order: DMA for s+2 must issue after this stage's ds_reads
        // and before the epilogue stores (vmcnt accounting depends on it).
        __builtin_amdgcn_sched_barrier(0);
        stage_issue(s + 2);
        __builtin_amdgcn_sched_barrier(0);
      }
    }

    // ---- epilogue: D row(o) = nt*16 + quad*4 + r, col(batch) = m15 ----
    float* op = out + (size_t)(btile + m15) * 65536
                    + (size_t)(ci * 8) * 256 + cj * 8;
    #pragma unroll
    for (int nt = 0; nt < 4; ++nt) {
      const int o0 = nt * 16 + quad * 4;             // o0..o0+3, same oh row
      float4 b4 = *(const float4*)&bs[o0];
      float4 res;
      res.x = fmaxf(acc[nt][0] + b4.x, 0.f);
      res.y = fmaxf(acc[nt][1] + b4.y, 0.f);
      res.z = fmaxf(acc[nt][2] + b4.z, 0.f);
      res.w = fmaxf(acc[nt][3] + b4.w, 0.f);
      *(float4*)&op[(o0 >> 3) * 256 + (o0 & 7)] = res;
    }
  }
}

extern "C" void kernel_launch(void* const* d_in, const int* in_sizes, int n_in,
                              void* d_out, int out_size, void* d_ws, size_t ws_size,
                              hipStream_t stream) {
  const float* x  = (const float*)d_in[0];
  const float* Wk = (const float*)d_in[1];
  const float* bk = (const float*)d_in[2];
  float* out = (float*)d_out;
  comp_kernel<<<dim3(1024), dim3(256), 0, stream>>>(x, Wk, bk, out);
}